// Round 1
// baseline (480.758 us; speedup 1.0000x reference)
//
#include <hip/hip_runtime.h>
#include <hip/hip_bf16.h>
#include <stdint.h>

// Problem constants
#define S_LEN 2048
#define DMODEL 4096
#define N_HQ 32
#define N_HKV 8
#define HD 128
#define NQKV 6144   // 4096 q + 1024 k + 1024 v
#define KOFF 4096
#define VOFF 5120

typedef __bf16 bf16x8 __attribute__((ext_vector_type(8)));
typedef __bf16 bf16x4 __attribute__((ext_vector_type(4)));
typedef float f32x4 __attribute__((ext_vector_type(4)));

static __device__ __forceinline__ f32x4 mfma16(bf16x8 a, bf16x8 b, f32x4 c) {
  return __builtin_amdgcn_mfma_f32_16x16x32_bf16(a, b, c, 0, 0, 0);
}

typedef const __attribute__((address_space(1))) void* gas_cvp;
typedef __attribute__((address_space(3))) void* las_vp;

// ---------------- fp32 -> bf16 elementwise convert (x) ----------------
__global__ __launch_bounds__(256) void cvt_f32_bf16(
    const float* __restrict__ in, __bf16* __restrict__ out)
{
  int i = blockIdx.x * 256 + threadIdx.x;
  float4 v = ((const float4*)in)[i];
  bf16x4 o = { (__bf16)v.x, (__bf16)v.y, (__bf16)v.z, (__bf16)v.w };
  *(bf16x4*)(out + 4*(size_t)i) = o;
}

// -------- fp32 [K,N] -> bf16 [N,K] transpose+scale, 64(k) x 32(n) tile -----
// Row-pairs packed into u32 (2 x bf16): coalesced float loads, u32 LDS words
// (stride 37: bank = (5c+rp)%32, bijective in c -> <=2-way), 4 B/lane stores.
static __device__ __forceinline__ void tr_tile(
    const float* __restrict__ src, __bf16* __restrict__ dst,
    int ins, int outs, float scale, int r0, int c0,
    uint32_t (*pt)[37], int t)
{
  int c = t & 31, r2 = t >> 5;          // load role: col 0..31, row-octet 0..7
#pragma unroll
  for (int i = 0; i < 4; i++) {
    int rp = r2 + 8*i;                  // row-pair 0..31
    const float* s0 = src + (size_t)(r0 + 2*rp) * ins + c0 + c;
    float f0 = s0[0];
    float f1 = s0[ins];
    uint16_t lo = __builtin_bit_cast(uint16_t, (__bf16)(f0 * scale));
    uint16_t hi = __builtin_bit_cast(uint16_t, (__bf16)(f1 * scale));
    pt[c][rp] = (uint32_t)lo | ((uint32_t)hi << 16);
  }
  __syncthreads();
  int oc = t >> 3, og = t & 7;          // store role: out-row 0..31, pair-octet
#pragma unroll
  for (int i = 0; i < 4; i++) {
    int rp = og + 8*i;
    *(uint32_t*)&dst[(size_t)(c0 + oc) * outs + r0 + 2*rp] = pt[oc][rp];
  }
}

// one launch for wq+wk+wv -> Wt[6144][4096]
__global__ __launch_bounds__(256) void prep_w_qkv(
    const float* __restrict__ wq, const float* __restrict__ wk,
    const float* __restrict__ wv, __bf16* __restrict__ Wt)
{
  __shared__ uint32_t pt[32][37];
  int bx = blockIdx.x;
  const float* src; int ins; float scale; int obase;
  if (bx < 128)      { src = wq; ins = 4096; scale = 0.12751295866442674f; obase = 0; }
  else if (bx < 160) { src = wk; ins = 1024; scale = 1.0f; obase = 4096; bx -= 128; }
  else               { src = wv; ins = 1024; scale = 1.0f; obase = 5120; bx -= 160; }
  tr_tile(src, Wt + (size_t)obase * 4096, ins, 4096, scale,
          (int)blockIdx.y * 64, bx * 32, pt, threadIdx.x);
}

__global__ __launch_bounds__(256) void prep_wo(
    const float* __restrict__ wo, __bf16* __restrict__ Wot)
{
  __shared__ uint32_t pt[32][37];
  tr_tile(wo, Wot, 4096, 4096, 1.0f,
          (int)blockIdx.y * 64, (int)blockIdx.x * 32, pt, threadIdx.x);
}

// ---------------- bf16 transpose (v -> vt), u16 moves ----------------
__global__ __launch_bounds__(256) void transpose_k(
    const uint16_t* __restrict__ in, uint16_t* __restrict__ out,
    int in_stride, int out_stride)
{
  __shared__ uint16_t tile[32][33];
  int tx = threadIdx.x & 31;
  int ty = threadIdx.x >> 5;
  size_t r0 = (size_t)blockIdx.y * 32;
  size_t c0 = (size_t)blockIdx.x * 32;
#pragma unroll
  for (int i = 0; i < 4; i++)
    tile[ty + i*8][tx] = in[(r0 + ty + i*8) * in_stride + c0 + tx];
  __syncthreads();
#pragma unroll
  for (int i = 0; i < 4; i++)
    out[(c0 + ty + i*8) * out_stride + r0 + tx] = tile[tx][ty + i*8];
}

// ---------------- GEMM: C[M,N] = A[M,K] @ Bt[N,K]^T, bf16 in, f32 acc -------
// m97 structure + BK=64 + XOR source-swizzle. 32 KB LDS.
// ROPE=true: apply RoPE in the epilogue to cols < 5120 (q & k regions).
// C-fragment col parity == lane&1, so the (even,odd) pair sits in adjacent
// lanes -> one __shfl_xor(v,1), applied to fp32 acc pre-rounding.
#define BKG 64
template <typename OutT, bool ROPE>
__global__ __launch_bounds__(256, 3) void gemm_bt(
    const __bf16* __restrict__ A,   // [M,K]
    const __bf16* __restrict__ Bt,  // [N,K]
    OutT* __restrict__ C,           // [M,N]
    int M, int N, int K,
    const float* __restrict__ cosb, const float* __restrict__ sinb)
{
  __shared__ __attribute__((aligned(16))) __bf16 Asl[128*BKG];
  __shared__ __attribute__((aligned(16))) __bf16 Bsl[128*BKG];
  int tid = threadIdx.x;
  int lane = tid & 63, wave = tid >> 6;
  int wm = wave >> 1, wn = wave & 1;
  int row16 = lane & 15, quad = lane >> 4;
  size_t m0 = (size_t)blockIdx.y * 128;
  size_t n0 = (size_t)blockIdx.x * 128;
  f32x4 acc[4][4] = {};

  for (int k0 = 0; k0 < K; k0 += BKG) {
    __syncthreads();
#pragma unroll
    for (int c = 0; c < 4; c++) {
      int u = c*256 + tid;
      int r = u >> 3;
      int swz = (u & 7) ^ (r & 7);           // source-chunk XOR swizzle
      const __bf16* ga = A + (m0 + r) * (size_t)K + k0 + swz*8;
      char* la = (char*)Asl + (size_t)(c*256 + wave*64) * 16;  // wave-uniform
      __builtin_amdgcn_global_load_lds((gas_cvp)ga, (las_vp)la, 16, 0, 0);
      const __bf16* gb = Bt + (n0 + r) * (size_t)K + k0 + swz*8;
      char* lb = (char*)Bsl + (size_t)(c*256 + wave*64) * 16;
      __builtin_amdgcn_global_load_lds((gas_cvp)gb, (las_vp)lb, 16, 0, 0);
    }
    __syncthreads();

#pragma unroll
    for (int kk = 0; kk < 2; kk++) {
      int sw = ((kk*4 + quad) ^ (row16 & 7)) * 8;   // de-swizzled chunk
      bf16x8 af[4], bfr[4];
#pragma unroll
      for (int i = 0; i < 4; i++)
        af[i] = *(const bf16x8*)&Asl[(wm*64 + i*16 + row16)*BKG + sw];
#pragma unroll
      for (int j = 0; j < 4; j++)
        bfr[j] = *(const bf16x8*)&Bsl[(wn*64 + j*16 + row16)*BKG + sw];
#pragma unroll
      for (int i = 0; i < 4; i++)
#pragma unroll
        for (int j = 0; j < 4; j++)
          acc[i][j] = mfma16(af[i], bfr[j], acc[i][j]);
    }
  }

  // epilogue: C/D layout col=lane&15, row=quad*4+reg (verified m89/m91)
  const bool doRope = ROPE && (n0 < 5120);   // tile-uniform (5120 % 128 == 0)
#pragma unroll
  for (int i = 0; i < 4; i++)
#pragma unroll
    for (int j = 0; j < 4; j++)
#pragma unroll
      for (int r = 0; r < 4; r++) {
        size_t row = m0 + wm*64 + i*16 + quad*4 + r;
        size_t col = n0 + wn*64 + j*16 + row16;
        float v = acc[i][j][r];
        if (doRope) {
          float other = __shfl_xor(v, 1);    // partner column's value
          int ii = (int)(col & 127) >> 1;    // rope index within head
          float cc = cosb[row*64 + ii];
          float ss = sinb[row*64 + ii];
          // even col: oe = te*c - to*s ; odd col: oo = te*s + to*c
          v = (lane & 1) ? (other*ss + v*cc) : (v*cc - other*ss);
        }
        C[row * (size_t)N + col] = (OutT)v;
      }
}

// ---------------- flash attention v4: uniform-work blocks -------------------
#define KB 64
#define PSTR 72    // Pl stride: 64 k + 8 pad (144 B, 2-way max)
__global__ __launch_bounds__(256, 2) void attn_k(
    const __bf16* __restrict__ qkv,   // [S, 6144]
    const __bf16* __restrict__ vt,    // [1024, S]  (v transposed)
    __bf16* __restrict__ attnout)     // [S, 4096]
{
  __shared__ __attribute__((aligned(16))) __bf16 Kl[KB*HD];      // 16 KB, swizzled
  __shared__ __attribute__((aligned(16))) __bf16 Vl[HD*KB];      // 16 KB, swizzled
  __shared__ __attribute__((aligned(16))) __bf16 Pl[4*32*PSTR];  // 18 KB
  int tid = threadIdx.x;
  int lane = tid & 63, wave = tid >> 6;
  int row16 = lane & 15, quad = lane >> 4;

  int b = blockIdx.x;
  int h = b & 31;
  int j = b >> 5;                      // 0..15
  int pr = j >> 1, hb = j & 1;
  int qt_h = 15 - pr;                  // 15..8
  int qt_l = pr;                       // 0..7
  int hkv = h >> 2;
  int h0 = qt_h*128 + hb*64 + wave*16; // heavy 16-row base
  int l0 = qt_l*128 + hb*64 + wave*16; // light 16-row base
  int ktd_h = 2*qt_h + hb;             // heavy diagonal chunk
  int ktd_l = 2*qt_l + hb;             // light diagonal chunk
  int nkt = ktd_h + 1;

  bf16x8 qf[2][4];
#pragma unroll
  for (int c = 0; c < 4; c++) {
    qf[0][c] = *(const bf16x8*)&qkv[(size_t)(h0 + row16)*NQKV + h*HD + c*32 + quad*8];
    qf[1][c] = *(const bf16x8*)&qkv[(size_t)(l0 + row16)*NQKV + h*HD + c*32 + quad*8];
  }

  f32x4 acc[2][8] = {};
  float lsum[2][4] = {};

  __bf16* Pw = &Pl[wave*32*PSTR];
  for (int kt = 0; kt < nkt; kt++) {
    int kb = kt*KB;
    __syncthreads();
#pragma unroll
    for (int c = 0; c < 4; c++) {
      int u = c*256 + tid;
      int kr = u >> 4;
      int kp = (u & 15) ^ (kr & 15);
      const __bf16* gk = &qkv[(size_t)(kb+kr)*NQKV + KOFF + hkv*HD + kp*8];
      char* lk = (char*)Kl + (size_t)(c*256 + wave*64) * 16;
      __builtin_amdgcn_global_load_lds((gas_cvp)gk, (las_vp)lk, 16, 0, 0);
      int dd = u >> 3;
      int vp = (u & 7) ^ (dd & 7);
      const __bf16* gv = &vt[(size_t)(hkv*HD + dd)*S_LEN + kb + vp*8];
      char* lv = (char*)Vl + (size_t)(c*256 + wave*64) * 16;
      __builtin_amdgcn_global_load_lds((gas_cvp)gv, (las_vp)lv, 16, 0, 0);
    }
    __syncthreads();

    int lightOn = (kt <= ktd_l);

    f32x4 s[2][4] = {};
#pragma unroll
    for (int c = 0; c < 4; c++) {
      bf16x8 kf[4];
#pragma unroll
      for (int jt = 0; jt < 4; jt++) {
        int pc = (c*4 + quad) ^ row16;
        kf[jt] = *(const bf16x8*)&Kl[(jt*16 + row16)*HD + pc*8];
      }
#pragma unroll
      for (int jt = 0; jt < 4; jt++)
        s[0][jt] = mfma16(qf[0][c], kf[jt], s[0][jt]);
      if (lightOn)
#pragma unroll
        for (int jt = 0; jt < 4; jt++)
          s[1][jt] = mfma16(qf[1][c], kf[jt], s[1][jt]);
    }

    if (kt == ktd_h) {
#pragma unroll
      for (int r = 0; r < 4; r++) {
        int rowl = quad*4 + r;
        int row_g = h0 + rowl;
#pragma unroll
        for (int jt = 0; jt < 4; jt++) {
          int col_g = kb + jt*16 + row16;
          float e = (col_g <= row_g) ? exp2f(s[0][jt][r]) : 0.0f;
          lsum[0][r] += e;
          Pw[rowl*PSTR + jt*16 + row16] = (__bf16)e;
        }
      }
    } else {
#pragma unroll
      for (int r = 0; r < 4; r++) {
        int rowl = quad*4 + r;
#pragma unroll
        for (int jt = 0; jt < 4; jt++) {
          float e = exp2f(s[0][jt][r]);
          lsum[0][r] += e;
          Pw[rowl*PSTR + jt*16 + row16] = (__bf16)e;
        }
      }
    }
    if (lightOn) {
      if (kt == ktd_l) {
#pragma unroll
        for (int r = 0; r < 4; r++) {
          int rowl = quad*4 + r;
#pragma unroll
          for (int jt = 0; jt < 4; jt++) {
            int col_g = kb + jt*16 + row16;
            float e = (col_g <= l0 + rowl) ? exp2f(s[1][jt][r]) : 0.0f;
            lsum[1][r] += e;
            Pw[(16+rowl)*PSTR + jt*16 + row16] = (__bf16)e;
          }
        }
      } else {
#pragma unroll
        for (int r = 0; r < 4; r++) {
          int rowl = quad*4 + r;
#pragma unroll
          for (int jt = 0; jt < 4; jt++) {
            float e = exp2f(s[1][jt][r]);
            lsum[1][r] += e;
            Pw[(16+rowl)*PSTR + jt*16 + row16] = (__bf16)e;
          }
        }
      }
    }

#pragma unroll
    for (int kk = 0; kk < 2; kk++) {
      bf16x8 pa0 = *(const bf16x8*)&Pw[(row16)*PSTR + kk*32 + quad*8];
      bf16x8 pa1 = *(const bf16x8*)&Pw[(16+row16)*PSTR + kk*32 + quad*8];
#pragma unroll
      for (int ct = 0; ct < 8; ct++) {
        int pv = (kk*4 + quad) ^ (row16 & 7);
        bf16x8 vb = *(const bf16x8*)&Vl[(ct*16 + row16)*KB + pv*8];
        acc[0][ct] = mfma16(pa0, vb, acc[0][ct]);
        if (lightOn) acc[1][ct] = mfma16(pa1, vb, acc[1][ct]);
      }
    }
  }

#pragma unroll
  for (int mt = 0; mt < 2; mt++)
#pragma unroll
    for (int r = 0; r < 4; r++) {
      float l = lsum[mt][r];
      l += __shfl_xor(l, 1);
      l += __shfl_xor(l, 2);
      l += __shfl_xor(l, 4);
      l += __shfl_xor(l, 8);
      lsum[mt][r] = 1.0f / l;
    }
#pragma unroll
  for (int mt = 0; mt < 2; mt++) {
    int base = (mt == 0) ? h0 : l0;
#pragma unroll
    for (int r = 0; r < 4; r++) {
      size_t qrow = (size_t)base + quad*4 + r;
      float inv = lsum[mt][r];
#pragma unroll
      for (int ct = 0; ct < 8; ct++)
        attnout[qrow*DMODEL + h*HD + ct*16 + row16] = (__bf16)(acc[mt][ct][r] * inv);
    }
  }
}

// ---------------- launch ----------------
extern "C" void kernel_launch(void* const* d_in, const int* in_sizes, int n_in,
                              void* d_out, int out_size, void* d_ws, size_t ws_size,
                              hipStream_t stream) {
  const float* x    = (const float*)d_in[0];
  const float* wq   = (const float*)d_in[1];
  const float* wk   = (const float*)d_in[2];
  const float* wv   = (const float*)d_in[3];
  const float* wo   = (const float*)d_in[4];
  const float* cosb = (const float*)d_in[5];
  const float* sinb = (const float*)d_in[6];
  float* out = (float*)d_out;

  // workspace layout (bf16 elems), peak ~96.5 MB with region reuse
  __bf16* ws   = (__bf16*)d_ws;
  __bf16* Wt   = ws;                               // [6144][4096] fused qkv^T
  __bf16* Wot  = ws;                               // [4096][4096], reuses Wt after gemm1
  __bf16* xb   = Wt  + (size_t)NQKV*DMODEL;        // [2048][4096] x in bf16
  __bf16* attn = xb;                               // [2048][4096], reuses xb after gemm1
  __bf16* qkv  = xb  + (size_t)S_LEN*DMODEL;       // [2048][6144]
  __bf16* vt   = qkv + (size_t)S_LEN*NQKV;         // [1024][2048]

  cvt_f32_bf16<<<8192,256,0,stream>>>(x, xb);
  // wq (scaled by log2(e)/sqrt(HD)) + wk + wv transposed in one launch
  prep_w_qkv<<<dim3(192,64),256,0,stream>>>(wq, wk, wv, Wt);

  // QKV GEMM with fused RoPE epilogue (q & k column tiles)
  gemm_bt<__bf16, true><<<dim3(NQKV/128, S_LEN/128),256,0,stream>>>(
      xb, Wt, qkv, S_LEN, NQKV, DMODEL, cosb, sinb);

  transpose_k<<<dim3(32,64),256,0,stream>>>((const uint16_t*)(qkv + VOFF), (uint16_t*)vt, NQKV, S_LEN);

  prep_wo<<<dim3(128,64),256,0,stream>>>(wo, Wot);

  attn_k<<<512,256,0,stream>>>(qkv, vt, attn);

  gemm_bt<float, false><<<dim3(DMODEL/128, S_LEN/128),256,0,stream>>>(
      attn, Wot, out, S_LEN, DMODEL, DMODEL, nullptr, nullptr);
}